// Round 4
// baseline (290.210 us; speedup 1.0000x reference)
//
#include <hip/hip_runtime.h>
#include <hip/hip_bf16.h>
#include <math.h>

#define NSUB 16
#define NLAB 8
#define KG 128
#define BN 16384
#define DD 1024

typedef float v4f __attribute__((ext_vector_type(4)));
typedef short short8v __attribute__((ext_vector_type(8)));

static __device__ __forceinline__ short f2bf(float f) {
    unsigned u = __builtin_bit_cast(unsigned, f);
    unsigned r = (u + 0x7fffu + ((u >> 16) & 1u)) >> 16;   // RNE
    return (short)r;
}

static __device__ __forceinline__ short8v pack_bf8(float4 lo, float4 hi) {
    union { short8v s; __hip_bfloat162 h[4]; } u;
    u.h[0] = __float22bfloat162_rn(float2{lo.x, lo.y});
    u.h[1] = __float22bfloat162_rn(float2{lo.z, lo.w});
    u.h[2] = __float22bfloat162_rn(float2{hi.x, hi.y});
    u.h[3] = __float22bfloat162_rn(float2{hi.z, hi.w});
    return u.s;
}

static __device__ __forceinline__ float dot4(float4 v) {
    return v.x * v.x + v.y * v.y + v.z * v.z + v.w * v.w;
}

// K0: gid + group histogram via LDS (16 blocks x 1024 -> 2048 global atomics)
__global__ __launch_bounds__(1024) void k0_gid(const int* __restrict__ subject,
                                               const int* __restrict__ labels,
                                               int* __restrict__ gid, int* __restrict__ cnt) {
    __shared__ int h[KG];
    int t = threadIdx.x;
    if (t < KG) h[t] = 0;
    __syncthreads();
    int b = blockIdx.x * 1024 + t;
    int g = subject[b] * NLAB + labels[b];
    gid[b] = g;
    atomicAdd(&h[g], 1);
    __syncthreads();
    if (t < KG && h[t]) atomicAdd(&cnt[t], h[t]);
}

// K0b: exclusive prefix over 128 counts -> offs, cursor
__global__ void k0b_offs(const int* __restrict__ cnt, int* __restrict__ offs,
                         int* __restrict__ cursor) {
    __shared__ int c[KG];
    int t = threadIdx.x;
    c[t] = cnt[t];
    __syncthreads();
    int o = 0;
    for (int j = 0; j < t; ++j) o += c[j];
    offs[t] = o;
    cursor[t] = o;
}

// K0c: block-local counting sort -> per-block chunk reservation (2048 global atomics)
__global__ __launch_bounds__(1024) void k0c_scatter(const int* __restrict__ gid,
                                                    int* __restrict__ cursor,
                                                    int* __restrict__ rowlist) {
    __shared__ int lcnt[KG], lbase[KG], lcur[KG];
    int t = threadIdx.x;
    if (t < KG) { lcnt[t] = 0; lcur[t] = 0; }
    __syncthreads();
    int b = blockIdx.x * 1024 + t;
    int g = gid[b];
    atomicAdd(&lcnt[g], 1);
    __syncthreads();
    if (t < KG) lbase[t] = lcnt[t] ? atomicAdd(&cursor[t], lcnt[t]) : 0;
    __syncthreads();
    int pos = lbase[g] + atomicAdd(&lcur[g], 1);
    rowlist[pos] = b;
}

// K1: centroid for (group g, d-quarter). No atomics: each block owns its output.
__global__ __launch_bounds__(256) void k1_centroid(const float* __restrict__ X,
                                                   const int* __restrict__ rowlist,
                                                   const int* __restrict__ offs,
                                                   const int* __restrict__ cnt,
                                                   float* __restrict__ centroid) {
    int g = blockIdx.x >> 2;
    int dq = blockIdx.x & 3;
    int d = dq * 256 + threadIdx.x;
    __shared__ int rows[512];
    int n = cnt[g], o = offs[g];
    if (n > 512) n = 512;
    for (int i = threadIdx.x; i < n; i += 256) rows[i] = rowlist[o + i];
    __syncthreads();
    float acc = 0.f;
    int i = 0;
    for (; i + 8 <= n; i += 8) {
        float v[16];
#pragma unroll
        for (int u = 0; u < 8; ++u) {
            size_t base = (size_t)rows[i + u] * 2048 + d;
            v[2 * u] = X[base];
            v[2 * u + 1] = X[base + 1024];
        }
#pragma unroll
        for (int u = 0; u < 16; ++u) acc += v[u];
    }
    for (; i < n; ++i) {
        size_t base = (size_t)rows[i] * 2048 + d;
        acc += X[base] + X[base + 1024];
    }
    centroid[(size_t)g * DD + d] = acc / (2.f * (float)n);
}

// K2b: centroid -> bf16 table + ||c||^2 per group. Block = one group.
__global__ __launch_bounds__(256) void k2b_cbf(const float* __restrict__ centroid,
                                               unsigned short* __restrict__ Cbf,
                                               float* __restrict__ cnorm) {
    __shared__ float wsum[4];
    int g = blockIdx.x, t = threadIdx.x;
    float4 v = *(const float4*)(centroid + (size_t)g * DD + t * 4);
    short4 bv = make_short4(f2bf(v.x), f2bf(v.y), f2bf(v.z), f2bf(v.w));
    *(short4*)(Cbf + (size_t)g * DD + t * 4) = bv;
    float s = dot4(v);
#pragma unroll
    for (int x = 32; x; x >>= 1) s += __shfl_xor(s, x, 64);
    int lane = t & 63, w = t >> 6;
    if (lane == 0) wsum[w] = s;
    __syncthreads();
    if (t == 0) cnorm[g] = wsum[0] + wsum[1] + wsum[2] + wsum[3];
}

// K5a: MFMA GEMM Dot = feat @ centroid^T (bf16, stored fp32) + rownorm = ||feat||^2.
// Wave = 32 rows x 128 groups; fragments loaded directly from global in MFMA
// fragment order (A: fp32 + packed cvt; B: bf16 table). Register double-buffered.
__global__ __launch_bounds__(256) void k5a_dot(const float* __restrict__ X,
                                               const unsigned short* __restrict__ Cbf,
                                               float* __restrict__ Dot,
                                               float* __restrict__ rownorm) {
    int t = threadIdx.x, lane = t & 63;
    int gw = blockIdx.x * 4 + (t >> 6);
    int row0 = gw * 32;
    int m = lane & 15, q = lane >> 4;
    int r0 = row0 + m, r1 = row0 + 16 + m;
    const float* a0p = X + (size_t)(r0 & (BN - 1)) * 2048 + (size_t)(r0 >> 14) * 1024 + q * 8;
    const float* a1p = X + (size_t)(r1 & (BN - 1)) * 2048 + (size_t)(r1 >> 14) * 1024 + q * 8;
    const unsigned short* bp = Cbf + (size_t)m * DD + q * 8;

    v4f acc[2][8];
#pragma unroll
    for (int i = 0; i < 2; ++i)
#pragma unroll
        for (int j = 0; j < 8; ++j) acc[i][j] = (v4f){0.f, 0.f, 0.f, 0.f};

    float s0 = 0.f, s1 = 0.f;
    float4 a0l = *(const float4*)(a0p), a0h = *(const float4*)(a0p + 4);
    float4 a1l = *(const float4*)(a1p), a1h = *(const float4*)(a1p + 4);
    s0 += dot4(a0l) + dot4(a0h);
    s1 += dot4(a1l) + dot4(a1h);
    short8v cb[8];
#pragma unroll
    for (int gt = 0; gt < 8; ++gt) cb[gt] = *(const short8v*)(bp + gt * 16 * DD);
    short8v ca0 = pack_bf8(a0l, a0h), ca1 = pack_bf8(a1l, a1h);

    for (int kc = 0; kc < 31; ++kc) {
        int k = (kc + 1) * 32;
        float4 na0l = *(const float4*)(a0p + k), na0h = *(const float4*)(a0p + k + 4);
        float4 na1l = *(const float4*)(a1p + k), na1h = *(const float4*)(a1p + k + 4);
        short8v nb[8];
#pragma unroll
        for (int gt = 0; gt < 8; ++gt) nb[gt] = *(const short8v*)(bp + gt * 16 * DD + k);
#pragma unroll
        for (int gt = 0; gt < 8; ++gt) {
            acc[0][gt] = __builtin_amdgcn_mfma_f32_16x16x32_bf16(ca0, cb[gt], acc[0][gt], 0, 0, 0);
            acc[1][gt] = __builtin_amdgcn_mfma_f32_16x16x32_bf16(ca1, cb[gt], acc[1][gt], 0, 0, 0);
        }
        s0 += dot4(na0l) + dot4(na0h);
        s1 += dot4(na1l) + dot4(na1h);
        ca0 = pack_bf8(na0l, na0h);
        ca1 = pack_bf8(na1l, na1h);
#pragma unroll
        for (int gt = 0; gt < 8; ++gt) cb[gt] = nb[gt];
    }
#pragma unroll
    for (int gt = 0; gt < 8; ++gt) {
        acc[0][gt] = __builtin_amdgcn_mfma_f32_16x16x32_bf16(ca0, cb[gt], acc[0][gt], 0, 0, 0);
        acc[1][gt] = __builtin_amdgcn_mfma_f32_16x16x32_bf16(ca1, cb[gt], acc[1][gt], 0, 0, 0);
    }

    // rownorm: sum k-slices across the 4 q-lanes sharing each row
    s0 += __shfl_xor(s0, 16, 64); s0 += __shfl_xor(s0, 32, 64);
    s1 += __shfl_xor(s1, 16, 64); s1 += __shfl_xor(s1, 32, 64);
    if (lane < 16) rownorm[r0] = s0;
    else if (lane < 32) rownorm[r1] = s1;

    // Dot store: C/D layout col = lane&15 (group sub-idx), row = q*4 + reg
#pragma unroll
    for (int tile = 0; tile < 2; ++tile)
#pragma unroll
        for (int reg = 0; reg < 4; ++reg) {
            int row = row0 + tile * 16 + q * 4 + reg;
#pragma unroll
            for (int gt = 0; gt < 8; ++gt)
                Dot[(size_t)row * KG + gt * 16 + m] = acc[tile][gt][reg];
        }
}

// K3b: dist from Dot + norms; LDS-binned sqrt(dist) accumulation, 128 atomics/block.
__global__ __launch_bounds__(1024) void k3b_dist(const float* __restrict__ Dot,
                                                 const float* __restrict__ rownorm,
                                                 const float* __restrict__ cnorm,
                                                 const int* __restrict__ gid,
                                                 float* __restrict__ sqrtsum) {
    __shared__ float h[KG];
    int t = threadIdx.x;
    if (t < KG) h[t] = 0.f;
    __syncthreads();
    int r = blockIdx.x * 1024 + t;
    int b = r & (BN - 1);
    int g = gid[b];
    float d2 = rownorm[r] - 2.f * Dot[(size_t)r * KG + g] + cnorm[g];
    d2 = fmaxf(d2, 0.f);
    atomicAdd(&h[g], sqrtf(sqrtf(d2)));   // sqrt(dist), dist = sqrt(d2)
    __syncthreads();
    if (t < KG && h[t] != 0.f) atomicAdd(&sqrtsum[t], h[t]);
}

// K4: density post-processing (max/where, rank-based quantiles, clip, mean-normalize)
__global__ void k4_density(const float* __restrict__ sqrtsum,
                           const int* __restrict__ cnt,
                           float* __restrict__ recipDen) {
    __shared__ float tmp[KG];
    __shared__ float d1s[KG];
    __shared__ float qv[4];
    int g = threadIdx.x;
    float cntf = 2.f * (float)cnt[g];
    float d0 = (sqrtsum[g] / cntf) / logf(cntf + 10.f);
    tmp[g] = d0;
    __syncthreads();
    float dmax = -INFINITY;
    for (int j = 0; j < KG; ++j) dmax = fmaxf(dmax, tmp[j]);
    float v = (cntf <= 1.f) ? dmax : d0;
    d1s[g] = v;
    __syncthreads();
    int less = 0, eq = 0;
    for (int j = 0; j < KG; ++j) {
        float u = d1s[j];
        less += (u < v) ? 1 : 0;
        eq += (u == v) ? 1 : 0;
    }
    // quantile(0.1): idx 12.7 -> 0.3*v[12]+0.7*v[13]; quantile(0.9): idx 114.3 -> 0.7*v[114]+0.3*v[115]
    const int ppos[4] = {12, 13, 114, 115};
    for (int q = 0; q < 4; ++q)
        if (less <= ppos[q] && ppos[q] < less + eq) qv[q] = v;
    __syncthreads();
    float q10 = 0.3f * qv[0] + 0.7f * qv[1];
    float q90 = 0.7f * qv[2] + 0.3f * qv[3];
    float d2 = fminf(fmaxf(v, q10), q90);
    __syncthreads();
    tmp[g] = d2;
    __syncthreads();
    float sum = 0.f;
    for (int j = 0; j < KG; ++j) sum += tmp[j];
    float mean = sum / (float)KG;
    float den = 0.1f * d2 / mean;
    recipDen[g] = 1.f / den;
}

// K5b: loss from Dot. Wave handles 32 rows; lane covers groups {lane, 64+lane}.
__global__ __launch_bounds__(256) void k5b_loss(const float* __restrict__ Dot,
                                                const int* __restrict__ gid,
                                                const float* __restrict__ recipDen,
                                                float* __restrict__ out) {
    __shared__ float wsum[4];
    int t = threadIdx.x, lane = t & 63, w = t >> 6;
    int gwave = blockIdx.x * 4 + w;
    int g0 = lane, g1 = 64 + lane;
    float rd0 = recipDen[g0], rd1 = recipDen[g1];
    int s0g = g0 >> 3, l0g = g0 & 7, s1g = g1 >> 3, l1g = g1 & 7;
    float ll = 0.f;
    for (int i = 0; i < 32; ++i) {
        int row = gwave * 32 + i;
        int b = row & (BN - 1);
        int gb = gid[b];
        int s = gb >> 3, l = gb & 7;
        float sim0 = Dot[(size_t)row * KG + g0] * rd0;
        float sim1 = Dot[(size_t)row * KG + g1] * rd1;
        float mx = fmaxf(sim0, sim1);
#pragma unroll
        for (int x = 1; x < 64; x <<= 1) mx = fmaxf(mx, __shfl_xor(mx, x, 64));
        bool p0 = (l0g == l) && (s0g != s);
        bool p1 = (l1g == l) && (s1g != s);
        float S = 0.f, P = 0.f;
        if (p0) { float pv = sim0 - mx; S += expf(pv); P += pv; }
        if (p1) { float pv = sim1 - mx; S += expf(pv); P += pv; }
#pragma unroll
        for (int x = 1; x < 64; x <<= 1) { S += __shfl_xor(S, x, 64); P += __shfl_xor(P, x, 64); }
        // 113 masked-out entries contribute exp(0)=1 each to the softmax denominator
        if (lane == 0) ll += logf(113.f + S) - P * (1.f / 15.f);
    }
    if (lane == 0) wsum[w] = ll;
    __syncthreads();
    if (t == 0) atomicAdd(out, (wsum[0] + wsum[1] + wsum[2] + wsum[3]) * (1.f / 32768.f));
}

extern "C" void kernel_launch(void* const* d_in, const int* in_sizes, int n_in,
                              void* d_out, int out_size, void* d_ws, size_t ws_size,
                              hipStream_t stream) {
    const float* X = (const float*)d_in[0];
    const int* subject = (const int*)d_in[1];
    const int* labels = (const int*)d_in[2];
    float* out = (float*)d_out;
    char* w = (char*)d_ws;
    int* gid = (int*)(w + 0);                        // 64 KB
    int* cnt = (int*)(w + 65536);                    // 512 B
    int* offs = (int*)(w + 66048);                   // 512 B
    int* cursor = (int*)(w + 66560);                 // 512 B
    float* sqrtsum = (float*)(w + 67072);            // 512 B
    float* recipDen = (float*)(w + 67584);           // 512 B
    float* cnorm = (float*)(w + 68096);              // 512 B
    int* rowlist = (int*)(w + 131072);               // 64 KB
    float* centroid = (float*)(w + 262144);          // 512 KB
    unsigned short* Cbf = (unsigned short*)(w + 786432);  // 256 KB
    float* rownorm = (float*)(w + 1048576);          // 128 KB
    float* Dot = (float*)(w + 2097152);              // 16 MB (total ~18 MB)

    hipMemsetAsync(cnt, 0, KG * sizeof(int), stream);
    hipMemsetAsync(sqrtsum, 0, KG * sizeof(float), stream);
    hipMemsetAsync(out, 0, sizeof(float), stream);

    k0_gid<<<16, 1024, 0, stream>>>(subject, labels, gid, cnt);
    k0b_offs<<<1, KG, 0, stream>>>(cnt, offs, cursor);
    k0c_scatter<<<16, 1024, 0, stream>>>(gid, cursor, rowlist);
    k1_centroid<<<KG * 4, 256, 0, stream>>>(X, rowlist, offs, cnt, centroid);
    k2b_cbf<<<KG, 256, 0, stream>>>(centroid, Cbf, cnorm);
    k5a_dot<<<256, 256, 0, stream>>>(X, Cbf, Dot, rownorm);
    k3b_dist<<<32, 1024, 0, stream>>>(Dot, rownorm, cnorm, gid, sqrtsum);
    k4_density<<<1, KG, 0, stream>>>(sqrtsum, cnt, recipDen);
    k5b_loss<<<256, 256, 0, stream>>>(Dot, gid, recipDen, out);
}

// Round 5
// 273.835 us; speedup vs baseline: 1.0598x; 1.0598x over previous
//
#include <hip/hip_runtime.h>
#include <hip/hip_bf16.h>
#include <math.h>

#define NSUB 16
#define NLAB 8
#define KG 128
#define BN 16384
#define DD 1024

typedef float v4f __attribute__((ext_vector_type(4)));
typedef short short8v __attribute__((ext_vector_type(8)));

static __device__ __forceinline__ short f2bf(float f) {
    unsigned u = __builtin_bit_cast(unsigned, f);
    unsigned r = (u + 0x7fffu + ((u >> 16) & 1u)) >> 16;   // RNE
    return (short)r;
}

static __device__ __forceinline__ short8v pack_bf8(float4 lo, float4 hi) {
    union { short8v s; __hip_bfloat162 h[4]; } u;
    u.h[0] = __float22bfloat162_rn(float2{lo.x, lo.y});
    u.h[1] = __float22bfloat162_rn(float2{lo.z, lo.w});
    u.h[2] = __float22bfloat162_rn(float2{hi.x, hi.y});
    u.h[3] = __float22bfloat162_rn(float2{hi.z, hi.w});
    return u.s;
}

static __device__ __forceinline__ float dot4(float4 v) {
    return v.x * v.x + v.y * v.y + v.z * v.z + v.w * v.w;
}

// K0: gid + group histogram via LDS (16 blocks x 1024 -> <=2048 global atomics)
__global__ __launch_bounds__(1024) void k0_gid(const int* __restrict__ subject,
                                               const int* __restrict__ labels,
                                               int* __restrict__ gid, int* __restrict__ cnt) {
    __shared__ int h[KG];
    int t = threadIdx.x;
    if (t < KG) h[t] = 0;
    __syncthreads();
    int b = blockIdx.x * 1024 + t;
    int g = subject[b] * NLAB + labels[b];
    gid[b] = g;
    atomicAdd(&h[g], 1);
    __syncthreads();
    if (t < KG && h[t]) atomicAdd(&cnt[t], h[t]);
}

// K0c: block-local counting sort; global prefix computed in-block from cnt.
// cursor must be zero-initialized (reservation counters).
__global__ __launch_bounds__(1024) void k0c_scatter(const int* __restrict__ gid,
                                                    const int* __restrict__ cnt,
                                                    int* __restrict__ cursor,
                                                    int* __restrict__ rowlist) {
    __shared__ int cval[KG], coff[KG], lcnt[KG], lbase[KG], lcur[KG];
    int t = threadIdx.x;
    if (t < KG) { cval[t] = cnt[t]; lcnt[t] = 0; lcur[t] = 0; }
    __syncthreads();
    if (t < KG) {
        int o = 0;
        for (int j = 0; j < t; ++j) o += cval[j];
        coff[t] = o;
    }
    int b = blockIdx.x * 1024 + t;
    int g = gid[b];
    atomicAdd(&lcnt[g], 1);
    __syncthreads();
    if (t < KG) lbase[t] = coff[t] + (lcnt[t] ? atomicAdd(&cursor[t], lcnt[t]) : 0);
    __syncthreads();
    rowlist[lbase[g] + atomicAdd(&lcur[g], 1)] = b;
}

// K1: centroid slice for (group g, d-quarter) -> bf16 Cbf + partial ||c||^2.
// offs computed in-block from cnt; no fp32 centroid buffer.
__global__ __launch_bounds__(256) void k1_centroid(const float* __restrict__ X,
                                                   const int* __restrict__ rowlist,
                                                   const int* __restrict__ cnt,
                                                   unsigned short* __restrict__ Cbf,
                                                   float* __restrict__ cnorm) {
    int g = blockIdx.x >> 2;
    int dq = blockIdx.x & 3;
    int t = threadIdx.x, d = dq * 256 + t;
    int lane = t & 63, w = t >> 6;
    __shared__ int rows[512];
    __shared__ int sh_no[2];
    __shared__ float wsum[4];
    if (w == 0) {
        int v = 0;
        if (lane < g) v += cnt[lane];
        if (lane + 64 < g) v += cnt[lane + 64];
#pragma unroll
        for (int x = 32; x; x >>= 1) v += __shfl_xor(v, x, 64);
        if (lane == 0) { sh_no[0] = v; sh_no[1] = cnt[g]; }
    }
    __syncthreads();
    int o = sh_no[0], n = min(sh_no[1], 512);
    for (int i = t; i < n; i += 256) rows[i] = rowlist[o + i];
    __syncthreads();
    float acc = 0.f;
    int i = 0;
    for (; i + 8 <= n; i += 8) {
        float v[16];
#pragma unroll
        for (int u = 0; u < 8; ++u) {
            size_t base = (size_t)rows[i + u] * 2048 + d;
            v[2 * u] = X[base];
            v[2 * u + 1] = X[base + 1024];
        }
#pragma unroll
        for (int u = 0; u < 16; ++u) acc += v[u];
    }
    for (; i < n; ++i) {
        size_t base = (size_t)rows[i] * 2048 + d;
        acc += X[base] + X[base + 1024];
    }
    float c = acc / (2.f * (float)n);
    Cbf[(size_t)g * DD + d] = (unsigned short)f2bf(c);
    float s = c * c;
#pragma unroll
    for (int x = 32; x; x >>= 1) s += __shfl_xor(s, x, 64);
    if (lane == 0) wsum[w] = s;
    __syncthreads();
    if (t == 0) atomicAdd(&cnorm[g], wsum[0] + wsum[1] + wsum[2] + wsum[3]);
}

// K5a: depth-2 pipelined MFMA GEMM Dot = feat @ centroid^T (bf16 -> fp32) with
// fused rownorm + own-group distance -> sqrtsum (LDS-binned). Wave = 32 rows.
__global__ __launch_bounds__(256) void k5a_dot(const float* __restrict__ X,
                                               const unsigned short* __restrict__ Cbf,
                                               const int* __restrict__ gid,
                                               const float* __restrict__ cnorm,
                                               float* __restrict__ Dot,
                                               float* __restrict__ sqrtsum) {
    __shared__ float h[KG];
    int t = threadIdx.x, lane = t & 63;
    if (t < KG) h[t] = 0.f;
    __syncthreads();
    int gw = blockIdx.x * 4 + (t >> 6);
    int row0 = gw * 32;
    int m = lane & 15, q = lane >> 4;
    int r0 = row0 + m, r1 = row0 + 16 + m;
    const float* a0p = X + (size_t)(r0 & (BN - 1)) * 2048 + (size_t)(r0 >> 14) * 1024 + q * 8;
    const float* a1p = X + (size_t)(r1 & (BN - 1)) * 2048 + (size_t)(r1 >> 14) * 1024 + q * 8;
    const unsigned short* bp = Cbf + (size_t)m * DD + q * 8;

    v4f acc[2][8];
#pragma unroll
    for (int i = 0; i < 2; ++i)
#pragma unroll
        for (int j = 0; j < 8; ++j) acc[i][j] = (v4f){0.f, 0.f, 0.f, 0.f};

    float s0 = 0.f, s1 = 0.f;
    // prologue: stages 0,1 packed; stages 2,3 fp32 in flight; B stages 0,1 resident
    short8v caA0, caA1, caB0, caB1, cbA[8], cbB[8];
    {
        float4 t0l = *(const float4*)(a0p), t0h = *(const float4*)(a0p + 4);
        float4 t1l = *(const float4*)(a1p), t1h = *(const float4*)(a1p + 4);
        s0 += dot4(t0l) + dot4(t0h); s1 += dot4(t1l) + dot4(t1h);
        caA0 = pack_bf8(t0l, t0h); caA1 = pack_bf8(t1l, t1h);
        float4 u0l = *(const float4*)(a0p + 32), u0h = *(const float4*)(a0p + 36);
        float4 u1l = *(const float4*)(a1p + 32), u1h = *(const float4*)(a1p + 36);
        s0 += dot4(u0l) + dot4(u0h); s1 += dot4(u1l) + dot4(u1h);
        caB0 = pack_bf8(u0l, u0h); caB1 = pack_bf8(u1l, u1h);
#pragma unroll
        for (int gt = 0; gt < 8; ++gt) {
            cbA[gt] = *(const short8v*)(bp + gt * 16 * DD);
            cbB[gt] = *(const short8v*)(bp + gt * 16 * DD + 32);
        }
    }
    float4 pA0l = *(const float4*)(a0p + 64), pA0h = *(const float4*)(a0p + 68);
    float4 pA1l = *(const float4*)(a1p + 64), pA1h = *(const float4*)(a1p + 68);
    float4 pB0l = *(const float4*)(a0p + 96), pB0h = *(const float4*)(a0p + 100);
    float4 pB1l = *(const float4*)(a1p + 96), pB1h = *(const float4*)(a1p + 100);

    for (int kc = 0; kc < 32; kc += 2) {
        // even sub-iteration: MFMA stage kc; pack stage kc+2; load stage kc+4
        {
            int kb = (kc + 2 <= 31 ? kc + 2 : 31) * 32;
            short8v nb[8];
#pragma unroll
            for (int gt = 0; gt < 8; ++gt) nb[gt] = *(const short8v*)(bp + gt * 16 * DD + kb);
#pragma unroll
            for (int gt = 0; gt < 8; ++gt) {
                acc[0][gt] = __builtin_amdgcn_mfma_f32_16x16x32_bf16(caA0, cbA[gt], acc[0][gt], 0, 0, 0);
                acc[1][gt] = __builtin_amdgcn_mfma_f32_16x16x32_bf16(caA1, cbA[gt], acc[1][gt], 0, 0, 0);
            }
            if (kc < 30) {
                s0 += dot4(pA0l) + dot4(pA0h); s1 += dot4(pA1l) + dot4(pA1h);
                caA0 = pack_bf8(pA0l, pA0h); caA1 = pack_bf8(pA1l, pA1h);
                int kf = (kc + 4 <= 31 ? kc + 4 : 0) * 32;
                pA0l = *(const float4*)(a0p + kf); pA0h = *(const float4*)(a0p + kf + 4);
                pA1l = *(const float4*)(a1p + kf); pA1h = *(const float4*)(a1p + kf + 4);
            }
#pragma unroll
            for (int gt = 0; gt < 8; ++gt) cbA[gt] = nb[gt];
        }
        // odd sub-iteration: MFMA stage kc+1; pack stage kc+3; load stage kc+5
        {
            int kb = (kc + 3 <= 31 ? kc + 3 : 31) * 32;
            short8v nb[8];
#pragma unroll
            for (int gt = 0; gt < 8; ++gt) nb[gt] = *(const short8v*)(bp + gt * 16 * DD + kb);
#pragma unroll
            for (int gt = 0; gt < 8; ++gt) {
                acc[0][gt] = __builtin_amdgcn_mfma_f32_16x16x32_bf16(caB0, cbB[gt], acc[0][gt], 0, 0, 0);
                acc[1][gt] = __builtin_amdgcn_mfma_f32_16x16x32_bf16(caB1, cbB[gt], acc[1][gt], 0, 0, 0);
            }
            if (kc < 30) {
                s0 += dot4(pB0l) + dot4(pB0h); s1 += dot4(pB1l) + dot4(pB1h);
                caB0 = pack_bf8(pB0l, pB0h); caB1 = pack_bf8(pB1l, pB1h);
                int kf = (kc + 5 <= 31 ? kc + 5 : 0) * 32;
                pB0l = *(const float4*)(a0p + kf); pB0h = *(const float4*)(a0p + kf + 4);
                pB1l = *(const float4*)(a1p + kf); pB1h = *(const float4*)(a1p + kf + 4);
            }
#pragma unroll
            for (int gt = 0; gt < 8; ++gt) cbB[gt] = nb[gt];
        }
    }

    // rownorm: all lanes end with s0 = ||row0+(lane&15)||^2, s1 = ||row0+16+(lane&15)||^2
    s0 += __shfl_xor(s0, 16, 64); s0 += __shfl_xor(s0, 32, 64);
    s1 += __shfl_xor(s1, 16, 64); s1 += __shfl_xor(s1, 32, 64);

    // epilogue: C/D layout col = lane&15 (group sub-idx), row = q*4 + reg.
    // Store Dot; owner lane (m == g&15) also accumulates sqrt(dist) into LDS bins.
#pragma unroll
    for (int tile = 0; tile < 2; ++tile)
#pragma unroll
        for (int reg = 0; reg < 4; ++reg) {
            int row = row0 + tile * 16 + q * 4 + reg;
            int b = row & (BN - 1);
            int g = gid[b];
            float own = 0.f;
#pragma unroll
            for (int gt = 0; gt < 8; ++gt) {
                float v = acc[tile][gt][reg];
                Dot[(size_t)row * KG + gt * 16 + m] = v;
                if ((g >> 4) == gt) own = v;
            }
            float rn = __shfl(tile ? s1 : s0, q * 4 + reg, 64);
            if ((g & 15) == m) {
                float d2 = fmaxf(rn - 2.f * own + cnorm[g], 0.f);
                atomicAdd(&h[g], sqrtf(sqrtf(d2)));   // sqrt(dist), dist = sqrt(d2)
            }
        }
    __syncthreads();
    if (t < KG && h[t] != 0.f) atomicAdd(&sqrtsum[t], h[t]);
}

// K5b: density post-processing (inlined per block) + loss, thread-per-row.
__global__ __launch_bounds__(256) void k5b_loss(const float* __restrict__ Dot,
                                                const int* __restrict__ gid,
                                                const float* __restrict__ sqrtsum,
                                                const int* __restrict__ cnt,
                                                float* __restrict__ out) {
    __shared__ float tmp[KG], d1s[KG], qv[4];
    __shared__ float recipDen[KG];
    __shared__ float wsum[4];
    int t = threadIdx.x;
    // ---- density (threads 0..127; all threads hit barriers) ----
    float cntf = 0.f, d0 = 0.f, v = 0.f;
    if (t < KG) {
        cntf = 2.f * (float)cnt[t];
        d0 = (sqrtsum[t] / cntf) / logf(cntf + 10.f);
        tmp[t] = d0;
    }
    __syncthreads();
    if (t < KG) {
        float dmax = -INFINITY;
        for (int j = 0; j < KG; ++j) dmax = fmaxf(dmax, tmp[j]);
        v = (cntf <= 1.f) ? dmax : d0;
        d1s[t] = v;
    }
    __syncthreads();
    if (t < KG) {
        int less = 0, eq = 0;
        for (int j = 0; j < KG; ++j) {
            float u = d1s[j];
            less += (u < v) ? 1 : 0;
            eq += (u == v) ? 1 : 0;
        }
        // quantile(0.1): idx 12.7 -> 0.3*v[12]+0.7*v[13]; quantile(0.9): 0.7*v[114]+0.3*v[115]
        const int ppos[4] = {12, 13, 114, 115};
        for (int qq = 0; qq < 4; ++qq)
            if (less <= ppos[qq] && ppos[qq] < less + eq) qv[qq] = v;
    }
    __syncthreads();
    if (t < KG) {
        float q10 = 0.3f * qv[0] + 0.7f * qv[1];
        float q90 = 0.7f * qv[2] + 0.3f * qv[3];
        tmp[t] = fminf(fmaxf(v, q10), q90);
    }
    __syncthreads();
    if (t < KG) {
        float sum = 0.f;
        for (int j = 0; j < KG; ++j) sum += tmp[j];
        float mean = sum / (float)KG;
        recipDen[t] = mean / (0.1f * tmp[t]);   // 1/den
    }
    __syncthreads();
    // ---- loss: one thread per row ----
    int row = blockIdx.x * 256 + t;
    int b = row & (BN - 1);
    int g = gid[b];
    int s = g >> 3, l = g & 7;
    int lp = (l >> 2) & 1, lc = l & 3;
    const float4* dp = (const float4*)(Dot + (size_t)row * KG);
    float mx = -INFINITY;
    float psave[16];
#pragma unroll
    for (int c = 0; c < 32; ++c) {
        float4 dv = dp[c];
        float4 rv = *(const float4*)&recipDen[c * 4];
        float x0 = dv.x * rv.x, x1 = dv.y * rv.y, x2 = dv.z * rv.z, x3 = dv.w * rv.w;
        mx = fmaxf(mx, fmaxf(fmaxf(x0, x1), fmaxf(x2, x3)));
        if ((c & 1) == lp) {
            float sel = (lc == 0) ? x0 : (lc == 1) ? x1 : (lc == 2) ? x2 : x3;
            psave[c >> 1] = sel;
        }
    }
    float S = 0.f, P = 0.f;
#pragma unroll
    for (int j = 0; j < 16; ++j) {
        float pv = psave[j] - mx;
        float e = expf(pv);
        bool use = (j != s);
        S += use ? e : 0.f;
        P += use ? pv : 0.f;
    }
    // 113 masked-out entries contribute exp(0)=1 each to the softmax denominator
    float ll = logf(113.f + S) - P * (1.f / 15.f);
#pragma unroll
    for (int x = 32; x; x >>= 1) ll += __shfl_xor(ll, x, 64);
    int lane = t & 63, w = t >> 6;
    if (lane == 0) wsum[w] = ll;
    __syncthreads();
    if (t == 0) atomicAdd(out, (wsum[0] + wsum[1] + wsum[2] + wsum[3]) * (1.f / 32768.f));
}

extern "C" void kernel_launch(void* const* d_in, const int* in_sizes, int n_in,
                              void* d_out, int out_size, void* d_ws, size_t ws_size,
                              hipStream_t stream) {
    const float* X = (const float*)d_in[0];
    const int* subject = (const int*)d_in[1];
    const int* labels = (const int*)d_in[2];
    float* out = (float*)d_out;
    char* w = (char*)d_ws;
    int* gid = (int*)(w + 0);                        // 64 KB
    int* cnt = (int*)(w + 65536);                    // 512 B  ┐
    float* sqrtsum = (float*)(w + 66048);            // 512 B  │ one 2 KB memset
    float* cnorm = (float*)(w + 66560);              // 512 B  │
    int* cursor = (int*)(w + 67072);                 // 512 B  ┘
    int* rowlist = (int*)(w + 131072);               // 64 KB
    unsigned short* Cbf = (unsigned short*)(w + 262144);  // 256 KB
    float* Dot = (float*)(w + 2097152);              // 16 MB

    hipMemsetAsync(w + 65536, 0, 2048, stream);
    hipMemsetAsync(out, 0, sizeof(float), stream);

    k0_gid<<<16, 1024, 0, stream>>>(subject, labels, gid, cnt);
    k0c_scatter<<<16, 1024, 0, stream>>>(gid, cnt, cursor, rowlist);
    k1_centroid<<<KG * 4, 256, 0, stream>>>(X, rowlist, cnt, Cbf, cnorm);
    k5a_dot<<<256, 256, 0, stream>>>(X, Cbf, gid, cnorm, Dot, sqrtsum);
    k5b_loss<<<128, 256, 0, stream>>>(Dot, gid, sqrtsum, cnt, out);
}

// Round 6
// 270.518 us; speedup vs baseline: 1.0728x; 1.0123x over previous
//
#include <hip/hip_runtime.h>
#include <hip/hip_bf16.h>
#include <math.h>

#define NSUB 16
#define NLAB 8
#define KG 128
#define BN 16384
#define DD 1024

typedef float v4f __attribute__((ext_vector_type(4)));
typedef short short8v __attribute__((ext_vector_type(8)));

static __device__ __forceinline__ short f2bf(float f) {
    unsigned u = __builtin_bit_cast(unsigned, f);
    unsigned r = (u + 0x7fffu + ((u >> 16) & 1u)) >> 16;   // RNE
    return (short)r;
}

static __device__ __forceinline__ short8v pack_bf8(float4 lo, float4 hi) {
    union { short8v s; __hip_bfloat162 h[4]; } u;
    u.h[0] = __float22bfloat162_rn(float2{lo.x, lo.y});
    u.h[1] = __float22bfloat162_rn(float2{lo.z, lo.w});
    u.h[2] = __float22bfloat162_rn(float2{hi.x, hi.y});
    u.h[3] = __float22bfloat162_rn(float2{hi.z, hi.w});
    return u.s;
}

static __device__ __forceinline__ float dot4(float4 v) {
    return v.x * v.x + v.y * v.y + v.z * v.z + v.w * v.w;
}

// K0: gid + per-block group histogram (plain stores; no global atomics, no memset)
__global__ __launch_bounds__(1024) void k0_gid(const int* __restrict__ subject,
                                               const int* __restrict__ labels,
                                               int* __restrict__ gid, int* __restrict__ hist) {
    __shared__ int h[KG];
    int t = threadIdx.x;
    if (t < KG) h[t] = 0;
    __syncthreads();
    int b = blockIdx.x * 1024 + t;
    int g = subject[b] * NLAB + labels[b];
    gid[b] = g;
    atomicAdd(&h[g], 1);
    __syncthreads();
    if (t < KG) hist[blockIdx.x * KG + t] = h[t];
}

// K0c: counting sort with deterministic block bases from hist matrix (no cursor).
// Block bi's slice of group g starts at globalPrefix(g) + sum_{bj<bi} hist[bj][g].
__global__ __launch_bounds__(1024) void k0c_scatter(const int* __restrict__ gid,
                                                    const int* __restrict__ hist,
                                                    int* __restrict__ cnt,
                                                    int* __restrict__ rowlist) {
    __shared__ int tots[KG], base0[KG], lcur[KG];
    int t = threadIdx.x, bi = blockIdx.x;
    if (t < KG) {
        int tot = 0, pre = 0;
#pragma unroll
        for (int j = 0; j < 16; ++j) {
            int v = hist[j * KG + t];
            tot += v;
            if (j < bi) pre += v;
        }
        tots[t] = tot;
        base0[t] = pre;
        lcur[t] = 0;
        if (bi == 0) cnt[t] = tot;
    }
    __syncthreads();
    if (t < KG) {
        int o = 0;
        for (int j = 0; j < t; ++j) o += tots[j];
        base0[t] += o;
    }
    __syncthreads();
    int b = bi * 1024 + t;
    int g = gid[b];
    rowlist[base0[g] + atomicAdd(&lcur[g], 1)] = b;
}

// K1: centroid slice for (group g, d-half) -> bf16 Cbf + partial ||c||^2 (plain store).
// 2 KB HBM segments, 16-row unroll (256 B in flight per thread).
__global__ __launch_bounds__(256) void k1_centroid(const float* __restrict__ X,
                                                   const int* __restrict__ rowlist,
                                                   const int* __restrict__ cnt,
                                                   unsigned short* __restrict__ Cbf,
                                                   float* __restrict__ cnormPart) {
    int g = blockIdx.x >> 1;
    int half = blockIdx.x & 1;
    int t = threadIdx.x, lane = t & 63, w = t >> 6;
    int d = half * 512 + t * 2;
    __shared__ int rows[512];
    __shared__ int sh_no[2];
    __shared__ float wsum[4];
    if (w == 0) {
        int v = 0;
        if (lane < g) v += cnt[lane];
        if (lane + 64 < g) v += cnt[lane + 64];
#pragma unroll
        for (int x = 32; x; x >>= 1) v += __shfl_xor(v, x, 64);
        if (lane == 0) { sh_no[0] = v; sh_no[1] = cnt[g]; }
    }
    __syncthreads();
    int o = sh_no[0], n = min(sh_no[1], 512);
    for (int i = t; i < n; i += 256) rows[i] = rowlist[o + i];
    __syncthreads();
    float ax = 0.f, ay = 0.f;
    int i = 0;
    for (; i + 16 <= n; i += 16) {
        float2 v[32];
#pragma unroll
        for (int u = 0; u < 16; ++u) {
            size_t base = (size_t)rows[i + u] * 2048 + d;
            v[2 * u] = *(const float2*)(X + base);
            v[2 * u + 1] = *(const float2*)(X + base + 1024);
        }
#pragma unroll
        for (int u = 0; u < 32; ++u) { ax += v[u].x; ay += v[u].y; }
    }
    for (; i < n; ++i) {
        size_t base = (size_t)rows[i] * 2048 + d;
        float2 v0 = *(const float2*)(X + base);
        float2 v1 = *(const float2*)(X + base + 1024);
        ax += v0.x + v1.x; ay += v0.y + v1.y;
    }
    float inv = 1.f / (2.f * (float)n);
    float cx = ax * inv, cy = ay * inv;
    ushort2 cb = make_ushort2((unsigned short)f2bf(cx), (unsigned short)f2bf(cy));
    *(ushort2*)(Cbf + (size_t)g * DD + d) = cb;
    float s = cx * cx + cy * cy;
#pragma unroll
    for (int x = 32; x; x >>= 1) s += __shfl_xor(s, x, 64);
    if (lane == 0) wsum[w] = s;
    __syncthreads();
    if (t == 0) cnormPart[half * KG + g] = wsum[0] + wsum[1] + wsum[2] + wsum[3];
}

// K5a: depth-2 pipelined MFMA GEMM Dot = feat @ centroid^T (bf16 -> fp32) with
// fused rownorm + own-group distance -> per-block sqsPart (plain store). Wave = 32 rows.
__global__ __launch_bounds__(256) void k5a_dot(const float* __restrict__ X,
                                               const unsigned short* __restrict__ Cbf,
                                               const int* __restrict__ gid,
                                               const float* __restrict__ cnormPart,
                                               float* __restrict__ Dot,
                                               float* __restrict__ sqsPart) {
    __shared__ float h[KG];
    __shared__ float cnormS[KG];
    int t = threadIdx.x, lane = t & 63;
    if (t < KG) {
        h[t] = 0.f;
        cnormS[t] = cnormPart[t] + cnormPart[KG + t];
    }
    __syncthreads();
    int gw = blockIdx.x * 4 + (t >> 6);
    int row0 = gw * 32;
    int m = lane & 15, q = lane >> 4;
    int r0 = row0 + m, r1 = row0 + 16 + m;
    const float* a0p = X + (size_t)(r0 & (BN - 1)) * 2048 + (size_t)(r0 >> 14) * 1024 + q * 8;
    const float* a1p = X + (size_t)(r1 & (BN - 1)) * 2048 + (size_t)(r1 >> 14) * 1024 + q * 8;
    const unsigned short* bp = Cbf + (size_t)m * DD + q * 8;

    v4f acc[2][8];
#pragma unroll
    for (int i = 0; i < 2; ++i)
#pragma unroll
        for (int j = 0; j < 8; ++j) acc[i][j] = (v4f){0.f, 0.f, 0.f, 0.f};

    float s0 = 0.f, s1 = 0.f;
    // prologue: stages 0,1 packed; stages 2,3 fp32 in flight; B stages 0,1 resident
    short8v caA0, caA1, caB0, caB1, cbA[8], cbB[8];
    {
        float4 t0l = *(const float4*)(a0p), t0h = *(const float4*)(a0p + 4);
        float4 t1l = *(const float4*)(a1p), t1h = *(const float4*)(a1p + 4);
        s0 += dot4(t0l) + dot4(t0h); s1 += dot4(t1l) + dot4(t1h);
        caA0 = pack_bf8(t0l, t0h); caA1 = pack_bf8(t1l, t1h);
        float4 u0l = *(const float4*)(a0p + 32), u0h = *(const float4*)(a0p + 36);
        float4 u1l = *(const float4*)(a1p + 32), u1h = *(const float4*)(a1p + 36);
        s0 += dot4(u0l) + dot4(u0h); s1 += dot4(u1l) + dot4(u1h);
        caB0 = pack_bf8(u0l, u0h); caB1 = pack_bf8(u1l, u1h);
#pragma unroll
        for (int gt = 0; gt < 8; ++gt) {
            cbA[gt] = *(const short8v*)(bp + gt * 16 * DD);
            cbB[gt] = *(const short8v*)(bp + gt * 16 * DD + 32);
        }
    }
    float4 pA0l = *(const float4*)(a0p + 64), pA0h = *(const float4*)(a0p + 68);
    float4 pA1l = *(const float4*)(a1p + 64), pA1h = *(const float4*)(a1p + 68);
    float4 pB0l = *(const float4*)(a0p + 96), pB0h = *(const float4*)(a0p + 100);
    float4 pB1l = *(const float4*)(a1p + 96), pB1h = *(const float4*)(a1p + 100);

    for (int kc = 0; kc < 32; kc += 2) {
        // even sub-iteration: MFMA stage kc; pack stage kc+2; load stage kc+4
        {
            int kb = (kc + 2 <= 31 ? kc + 2 : 31) * 32;
            short8v nb[8];
#pragma unroll
            for (int gt = 0; gt < 8; ++gt) nb[gt] = *(const short8v*)(bp + gt * 16 * DD + kb);
#pragma unroll
            for (int gt = 0; gt < 8; ++gt) {
                acc[0][gt] = __builtin_amdgcn_mfma_f32_16x16x32_bf16(caA0, cbA[gt], acc[0][gt], 0, 0, 0);
                acc[1][gt] = __builtin_amdgcn_mfma_f32_16x16x32_bf16(caA1, cbA[gt], acc[1][gt], 0, 0, 0);
            }
            if (kc < 30) {
                s0 += dot4(pA0l) + dot4(pA0h); s1 += dot4(pA1l) + dot4(pA1h);
                caA0 = pack_bf8(pA0l, pA0h); caA1 = pack_bf8(pA1l, pA1h);
                int kf = (kc + 4 <= 31 ? kc + 4 : 0) * 32;
                pA0l = *(const float4*)(a0p + kf); pA0h = *(const float4*)(a0p + kf + 4);
                pA1l = *(const float4*)(a1p + kf); pA1h = *(const float4*)(a1p + kf + 4);
            }
#pragma unroll
            for (int gt = 0; gt < 8; ++gt) cbA[gt] = nb[gt];
        }
        // odd sub-iteration: MFMA stage kc+1; pack stage kc+3; load stage kc+5
        {
            int kb = (kc + 3 <= 31 ? kc + 3 : 31) * 32;
            short8v nb[8];
#pragma unroll
            for (int gt = 0; gt < 8; ++gt) nb[gt] = *(const short8v*)(bp + gt * 16 * DD + kb);
#pragma unroll
            for (int gt = 0; gt < 8; ++gt) {
                acc[0][gt] = __builtin_amdgcn_mfma_f32_16x16x32_bf16(caB0, cbB[gt], acc[0][gt], 0, 0, 0);
                acc[1][gt] = __builtin_amdgcn_mfma_f32_16x16x32_bf16(caB1, cbB[gt], acc[1][gt], 0, 0, 0);
            }
            if (kc < 30) {
                s0 += dot4(pB0l) + dot4(pB0h); s1 += dot4(pB1l) + dot4(pB1h);
                caB0 = pack_bf8(pB0l, pB0h); caB1 = pack_bf8(pB1l, pB1h);
                int kf = (kc + 5 <= 31 ? kc + 5 : 0) * 32;
                pB0l = *(const float4*)(a0p + kf); pB0h = *(const float4*)(a0p + kf + 4);
                pB1l = *(const float4*)(a1p + kf); pB1h = *(const float4*)(a1p + kf + 4);
            }
#pragma unroll
            for (int gt = 0; gt < 8; ++gt) cbB[gt] = nb[gt];
        }
    }

    // rownorm: all lanes end with s0 = ||row0+(lane&15)||^2, s1 = ||row0+16+(lane&15)||^2
    s0 += __shfl_xor(s0, 16, 64); s0 += __shfl_xor(s0, 32, 64);
    s1 += __shfl_xor(s1, 16, 64); s1 += __shfl_xor(s1, 32, 64);

    // epilogue: C/D layout col = lane&15 (group sub-idx), row = q*4 + reg.
    // Store Dot; owner lane (m == g&15) also accumulates sqrt(dist) into LDS bins.
#pragma unroll
    for (int tile = 0; tile < 2; ++tile)
#pragma unroll
        for (int reg = 0; reg < 4; ++reg) {
            int row = row0 + tile * 16 + q * 4 + reg;
            int b = row & (BN - 1);
            int g = gid[b];
            float own = 0.f;
#pragma unroll
            for (int gt = 0; gt < 8; ++gt) {
                float v = acc[tile][gt][reg];
                Dot[(size_t)row * KG + gt * 16 + m] = v;
                if ((g >> 4) == gt) own = v;
            }
            float rn = __shfl(tile ? s1 : s0, q * 4 + reg, 64);
            if ((g & 15) == m) {
                float d2 = fmaxf(rn - 2.f * own + cnormS[g], 0.f);
                atomicAdd(&h[g], sqrtf(sqrtf(d2)));   // sqrt(dist), dist = sqrt(d2)
            }
        }
    __syncthreads();
    if (t < KG) sqsPart[(size_t)blockIdx.x * KG + t] = h[t];
}

// K5b: density post-processing (per-block, from sqsPart partials) + loss, thread-per-row.
__global__ __launch_bounds__(256) void k5b_loss(const float* __restrict__ Dot,
                                                const int* __restrict__ gid,
                                                const float* __restrict__ sqsPart,
                                                const int* __restrict__ cnt,
                                                float* __restrict__ out) {
    __shared__ float tmp[KG], d1s[KG], qv[4];
    __shared__ float recipDen[KG];
    __shared__ float wsum[4];
    int t = threadIdx.x;
    // ---- density (threads 0..127; all threads hit barriers) ----
    float cntf = 0.f, d0 = 0.f, v = 0.f;
    if (t < KG) {
        float ss = 0.f;
        for (int j = 0; j < 256; j += 4)
            ss += sqsPart[(size_t)j * KG + t] + sqsPart[(size_t)(j + 1) * KG + t] +
                  sqsPart[(size_t)(j + 2) * KG + t] + sqsPart[(size_t)(j + 3) * KG + t];
        cntf = 2.f * (float)cnt[t];
        d0 = (ss / cntf) / logf(cntf + 10.f);
        tmp[t] = d0;
    }
    __syncthreads();
    if (t < KG) {
        float dmax = -INFINITY;
        for (int j = 0; j < KG; ++j) dmax = fmaxf(dmax, tmp[j]);
        v = (cntf <= 1.f) ? dmax : d0;
        d1s[t] = v;
    }
    __syncthreads();
    if (t < KG) {
        int less = 0, eq = 0;
        for (int j = 0; j < KG; ++j) {
            float u = d1s[j];
            less += (u < v) ? 1 : 0;
            eq += (u == v) ? 1 : 0;
        }
        // quantile(0.1): idx 12.7 -> 0.3*v[12]+0.7*v[13]; quantile(0.9): 0.7*v[114]+0.3*v[115]
        const int ppos[4] = {12, 13, 114, 115};
        for (int qq = 0; qq < 4; ++qq)
            if (less <= ppos[qq] && ppos[qq] < less + eq) qv[qq] = v;
    }
    __syncthreads();
    if (t < KG) {
        float q10 = 0.3f * qv[0] + 0.7f * qv[1];
        float q90 = 0.7f * qv[2] + 0.3f * qv[3];
        tmp[t] = fminf(fmaxf(v, q10), q90);
    }
    __syncthreads();
    if (t < KG) {
        float sum = 0.f;
        for (int j = 0; j < KG; ++j) sum += tmp[j];
        float mean = sum / (float)KG;
        recipDen[t] = mean / (0.1f * tmp[t]);   // 1/den
    }
    __syncthreads();
    // ---- loss: one thread per row ----
    int row = blockIdx.x * 256 + t;
    int b = row & (BN - 1);
    int g = gid[b];
    int s = g >> 3, l = g & 7;
    int lp = (l >> 2) & 1, lc = l & 3;
    const float4* dp = (const float4*)(Dot + (size_t)row * KG);
    float mx = -INFINITY;
    float psave[16];
#pragma unroll
    for (int c = 0; c < 32; ++c) {
        float4 dv = dp[c];
        float4 rv = *(const float4*)&recipDen[c * 4];
        float x0 = dv.x * rv.x, x1 = dv.y * rv.y, x2 = dv.z * rv.z, x3 = dv.w * rv.w;
        mx = fmaxf(mx, fmaxf(fmaxf(x0, x1), fmaxf(x2, x3)));
        if ((c & 1) == lp) {
            float sel = (lc == 0) ? x0 : (lc == 1) ? x1 : (lc == 2) ? x2 : x3;
            psave[c >> 1] = sel;
        }
    }
    float S = 0.f, P = 0.f;
#pragma unroll
    for (int j = 0; j < 16; ++j) {
        float pv = psave[j] - mx;
        float e = expf(pv);
        bool use = (j != s);
        S += use ? e : 0.f;
        P += use ? pv : 0.f;
    }
    // 113 masked-out entries contribute exp(0)=1 each to the softmax denominator
    float ll = logf(113.f + S) - P * (1.f / 15.f);
#pragma unroll
    for (int x = 32; x; x >>= 1) ll += __shfl_xor(ll, x, 64);
    int lane = t & 63, w = t >> 6;
    if (lane == 0) wsum[w] = ll;
    __syncthreads();
    if (t == 0) atomicAdd(out, (wsum[0] + wsum[1] + wsum[2] + wsum[3]) * (1.f / 32768.f));
}

extern "C" void kernel_launch(void* const* d_in, const int* in_sizes, int n_in,
                              void* d_out, int out_size, void* d_ws, size_t ws_size,
                              hipStream_t stream) {
    const float* X = (const float*)d_in[0];
    const int* subject = (const int*)d_in[1];
    const int* labels = (const int*)d_in[2];
    float* out = (float*)d_out;
    char* w = (char*)d_ws;
    int* gid = (int*)(w + 0);                          // 64 KB
    int* hist = (int*)(w + 65536);                     // 8 KB  (16 x 128)
    int* cnt = (int*)(w + 73728);                      // 512 B
    float* cnormPart = (float*)(w + 74240);            // 1 KB  (2 x 128)
    int* rowlist = (int*)(w + 131072);                 // 64 KB
    unsigned short* Cbf = (unsigned short*)(w + 262144);   // 256 KB
    float* sqsPart = (float*)(w + 524288);             // 128 KB (256 x 128)
    float* Dot = (float*)(w + 2097152);                // 16 MB

    hipMemsetAsync(out, 0, sizeof(float), stream);

    k0_gid<<<16, 1024, 0, stream>>>(subject, labels, gid, hist);
    k0c_scatter<<<16, 1024, 0, stream>>>(gid, hist, cnt, rowlist);
    k1_centroid<<<KG * 2, 256, 0, stream>>>(X, rowlist, cnt, Cbf, cnormPart);
    k5a_dot<<<256, 256, 0, stream>>>(X, Cbf, gid, cnormPart, Dot, sqsPart);
    k5b_loss<<<128, 256, 0, stream>>>(Dot, gid, sqsPart, cnt, out);
}

// Round 8
// 268.551 us; speedup vs baseline: 1.0807x; 1.0073x over previous
//
#include <hip/hip_runtime.h>
#include <hip/hip_bf16.h>
#include <math.h>

#define NSUB 16
#define NLAB 8
#define KG 128
#define BN 16384
#define DD 1024

typedef float v4f __attribute__((ext_vector_type(4)));
typedef short short8v __attribute__((ext_vector_type(8)));

static __device__ __forceinline__ short f2bf(float f) {
    unsigned u = __builtin_bit_cast(unsigned, f);
    unsigned r = (u + 0x7fffu + ((u >> 16) & 1u)) >> 16;   // RNE
    return (short)r;
}

static __device__ __forceinline__ float bf2f(unsigned short u) {
    unsigned v = ((unsigned)u) << 16;
    return __builtin_bit_cast(float, v);
}

static __device__ __forceinline__ short8v pack_bf8(float4 lo, float4 hi) {
    union { short8v s; __hip_bfloat162 h[4]; } u;
    u.h[0] = __float22bfloat162_rn(float2{lo.x, lo.y});
    u.h[1] = __float22bfloat162_rn(float2{lo.z, lo.w});
    u.h[2] = __float22bfloat162_rn(float2{hi.x, hi.y});
    u.h[3] = __float22bfloat162_rn(float2{hi.z, hi.w});
    return u.s;
}

static __device__ __forceinline__ float dot4(float4 v) {
    return v.x * v.x + v.y * v.y + v.z * v.z + v.w * v.w;
}

// K0: gid + per-block group histogram (plain stores; no global atomics, no memset)
__global__ __launch_bounds__(1024) void k0_gid(const int* __restrict__ subject,
                                               const int* __restrict__ labels,
                                               int* __restrict__ gid, int* __restrict__ hist) {
    __shared__ int h[KG];
    int t = threadIdx.x;
    if (t < KG) h[t] = 0;
    __syncthreads();
    int b = blockIdx.x * 1024 + t;
    int g = subject[b] * NLAB + labels[b];
    gid[b] = g;
    atomicAdd(&h[g], 1);
    __syncthreads();
    if (t < KG) hist[blockIdx.x * KG + t] = h[t];
}

// K0c: counting sort with deterministic block bases from hist matrix (no cursor).
__global__ __launch_bounds__(1024) void k0c_scatter(const int* __restrict__ gid,
                                                    const int* __restrict__ hist,
                                                    int* __restrict__ cnt,
                                                    int* __restrict__ rowlist) {
    __shared__ int tots[KG], base0[KG], lcur[KG];
    int t = threadIdx.x, bi = blockIdx.x;
    if (t < KG) {
        int tot = 0, pre = 0;
#pragma unroll
        for (int j = 0; j < 16; ++j) {
            int v = hist[j * KG + t];
            tot += v;
            if (j < bi) pre += v;
        }
        tots[t] = tot;
        base0[t] = pre;
        lcur[t] = 0;
        if (bi == 0) cnt[t] = tot;
    }
    __syncthreads();
    if (t < KG) {
        int o = 0;
        for (int j = 0; j < t; ++j) o += tots[j];
        base0[t] += o;
    }
    __syncthreads();
    int b = bi * 1024 + t;
    int g = gid[b];
    rowlist[base0[g] + atomicAdd(&lcur[g], 1)] = b;
}

// K1: centroid slice for (group g, d-half) -> bf16 Cbf + partial ||c||^2 (plain store).
__global__ __launch_bounds__(256) void k1_centroid(const float* __restrict__ X,
                                                   const int* __restrict__ rowlist,
                                                   const int* __restrict__ cnt,
                                                   unsigned short* __restrict__ Cbf,
                                                   float* __restrict__ cnormPart) {
    int g = blockIdx.x >> 1;
    int half = blockIdx.x & 1;
    int t = threadIdx.x, lane = t & 63, w = t >> 6;
    int d = half * 512 + t * 2;
    __shared__ int rows[512];
    __shared__ int sh_no[2];
    __shared__ float wsum[4];
    if (w == 0) {
        int v = 0;
        if (lane < g) v += cnt[lane];
        if (lane + 64 < g) v += cnt[lane + 64];
#pragma unroll
        for (int x = 32; x; x >>= 1) v += __shfl_xor(v, x, 64);
        if (lane == 0) { sh_no[0] = v; sh_no[1] = cnt[g]; }
    }
    __syncthreads();
    int o = sh_no[0], n = min(sh_no[1], 512);
    for (int i = t; i < n; i += 256) rows[i] = rowlist[o + i];
    __syncthreads();
    float ax = 0.f, ay = 0.f;
    int i = 0;
    for (; i + 16 <= n; i += 16) {
        float2 v[32];
#pragma unroll
        for (int u = 0; u < 16; ++u) {
            size_t base = (size_t)rows[i + u] * 2048 + d;
            v[2 * u] = *(const float2*)(X + base);
            v[2 * u + 1] = *(const float2*)(X + base + 1024);
        }
#pragma unroll
        for (int u = 0; u < 32; ++u) { ax += v[u].x; ay += v[u].y; }
    }
    for (; i < n; ++i) {
        size_t base = (size_t)rows[i] * 2048 + d;
        float2 v0 = *(const float2*)(X + base);
        float2 v1 = *(const float2*)(X + base + 1024);
        ax += v0.x + v1.x; ay += v0.y + v1.y;
    }
    float inv = 1.f / (2.f * (float)n);
    float cx = ax * inv, cy = ay * inv;
    ushort2 cb = make_ushort2((unsigned short)f2bf(cx), (unsigned short)f2bf(cy));
    *(ushort2*)(Cbf + (size_t)g * DD + d) = cb;
    float s = cx * cx + cy * cy;
#pragma unroll
    for (int x = 32; x; x >>= 1) s += __shfl_xor(s, x, 64);
    if (lane == 0) wsum[w] = s;
    __syncthreads();
    if (t == 0) cnormPart[half * KG + g] = wsum[0] + wsum[1] + wsum[2] + wsum[3];
}

// K5a: depth-2 pipelined MFMA GEMM Dot = feat @ centroid^T (bf16 -> fp32 acc) with
// fused rownorm + own-group distance -> per-block sqsPart. Dot stored as bf16.
__global__ __launch_bounds__(256) void k5a_dot(const float* __restrict__ X,
                                               const unsigned short* __restrict__ Cbf,
                                               const int* __restrict__ gid,
                                               const float* __restrict__ cnormPart,
                                               unsigned short* __restrict__ Dotb,
                                               float* __restrict__ sqsPart) {
    __shared__ float h[KG];
    __shared__ float cnormS[KG];
    int t = threadIdx.x, lane = t & 63;
    if (t < KG) {
        h[t] = 0.f;
        cnormS[t] = cnormPart[t] + cnormPart[KG + t];
    }
    __syncthreads();
    int gw = blockIdx.x * 4 + (t >> 6);
    int row0 = gw * 32;
    int m = lane & 15, q = lane >> 4;
    int r0 = row0 + m, r1 = row0 + 16 + m;
    const float* a0p = X + (size_t)(r0 & (BN - 1)) * 2048 + (size_t)(r0 >> 14) * 1024 + q * 8;
    const float* a1p = X + (size_t)(r1 & (BN - 1)) * 2048 + (size_t)(r1 >> 14) * 1024 + q * 8;
    const unsigned short* bp = Cbf + (size_t)m * DD + q * 8;

    v4f acc[2][8];
#pragma unroll
    for (int i = 0; i < 2; ++i)
#pragma unroll
        for (int j = 0; j < 8; ++j) acc[i][j] = (v4f){0.f, 0.f, 0.f, 0.f};

    float s0 = 0.f, s1 = 0.f;
    // prologue: stages 0,1 packed; stages 2,3 fp32 in flight; B stages 0,1 resident
    short8v caA0, caA1, caB0, caB1, cbA[8], cbB[8];
    {
        float4 t0l = *(const float4*)(a0p), t0h = *(const float4*)(a0p + 4);
        float4 t1l = *(const float4*)(a1p), t1h = *(const float4*)(a1p + 4);
        s0 += dot4(t0l) + dot4(t0h); s1 += dot4(t1l) + dot4(t1h);
        caA0 = pack_bf8(t0l, t0h); caA1 = pack_bf8(t1l, t1h);
        float4 u0l = *(const float4*)(a0p + 32), u0h = *(const float4*)(a0p + 36);
        float4 u1l = *(const float4*)(a1p + 32), u1h = *(const float4*)(a1p + 36);
        s0 += dot4(u0l) + dot4(u0h); s1 += dot4(u1l) + dot4(u1h);
        caB0 = pack_bf8(u0l, u0h); caB1 = pack_bf8(u1l, u1h);
#pragma unroll
        for (int gt = 0; gt < 8; ++gt) {
            cbA[gt] = *(const short8v*)(bp + gt * 16 * DD);
            cbB[gt] = *(const short8v*)(bp + gt * 16 * DD + 32);
        }
    }
    float4 pA0l = *(const float4*)(a0p + 64), pA0h = *(const float4*)(a0p + 68);
    float4 pA1l = *(const float4*)(a1p + 64), pA1h = *(const float4*)(a1p + 68);
    float4 pB0l = *(const float4*)(a0p + 96), pB0h = *(const float4*)(a0p + 100);
    float4 pB1l = *(const float4*)(a1p + 96), pB1h = *(const float4*)(a1p + 100);

    for (int kc = 0; kc < 32; kc += 2) {
        // even sub-iteration: MFMA stage kc; pack stage kc+2; load stage kc+4
        {
            int kb = (kc + 2 <= 31 ? kc + 2 : 31) * 32;
            short8v nb[8];
#pragma unroll
            for (int gt = 0; gt < 8; ++gt) nb[gt] = *(const short8v*)(bp + gt * 16 * DD + kb);
#pragma unroll
            for (int gt = 0; gt < 8; ++gt) {
                acc[0][gt] = __builtin_amdgcn_mfma_f32_16x16x32_bf16(caA0, cbA[gt], acc[0][gt], 0, 0, 0);
                acc[1][gt] = __builtin_amdgcn_mfma_f32_16x16x32_bf16(caA1, cbA[gt], acc[1][gt], 0, 0, 0);
            }
            if (kc < 30) {
                s0 += dot4(pA0l) + dot4(pA0h); s1 += dot4(pA1l) + dot4(pA1h);
                caA0 = pack_bf8(pA0l, pA0h); caA1 = pack_bf8(pA1l, pA1h);
                int kf = (kc + 4 <= 31 ? kc + 4 : 0) * 32;
                pA0l = *(const float4*)(a0p + kf); pA0h = *(const float4*)(a0p + kf + 4);
                pA1l = *(const float4*)(a1p + kf); pA1h = *(const float4*)(a1p + kf + 4);
            }
#pragma unroll
            for (int gt = 0; gt < 8; ++gt) cbA[gt] = nb[gt];
        }
        // odd sub-iteration: MFMA stage kc+1; pack stage kc+3; load stage kc+5
        {
            int kb = (kc + 3 <= 31 ? kc + 3 : 31) * 32;
            short8v nb[8];
#pragma unroll
            for (int gt = 0; gt < 8; ++gt) nb[gt] = *(const short8v*)(bp + gt * 16 * DD + kb);
#pragma unroll
            for (int gt = 0; gt < 8; ++gt) {
                acc[0][gt] = __builtin_amdgcn_mfma_f32_16x16x32_bf16(caB0, cbB[gt], acc[0][gt], 0, 0, 0);
                acc[1][gt] = __builtin_amdgcn_mfma_f32_16x16x32_bf16(caB1, cbB[gt], acc[1][gt], 0, 0, 0);
            }
            if (kc < 30) {
                s0 += dot4(pB0l) + dot4(pB0h); s1 += dot4(pB1l) + dot4(pB1h);
                caB0 = pack_bf8(pB0l, pB0h); caB1 = pack_bf8(pB1l, pB1h);
                int kf = (kc + 5 <= 31 ? kc + 5 : 0) * 32;
                pB0l = *(const float4*)(a0p + kf); pB0h = *(const float4*)(a0p + kf + 4);
                pB1l = *(const float4*)(a1p + kf); pB1h = *(const float4*)(a1p + kf + 4);
            }
#pragma unroll
            for (int gt = 0; gt < 8; ++gt) cbB[gt] = nb[gt];
        }
    }

    // rownorm: s0 = ||row0+(lane&15)||^2, s1 = ||row0+16+(lane&15)||^2 on all lanes
    s0 += __shfl_xor(s0, 16, 64); s0 += __shfl_xor(s0, 32, 64);
    s1 += __shfl_xor(s1, 16, 64); s1 += __shfl_xor(s1, 32, 64);

    // epilogue: C/D layout col = lane&15 (group sub-idx), row = q*4 + reg.
    // Store bf16 Dot; owner lane (m == g&15) accumulates own-dist from fp32 acc.
#pragma unroll
    for (int tile = 0; tile < 2; ++tile)
#pragma unroll
        for (int reg = 0; reg < 4; ++reg) {
            int row = row0 + tile * 16 + q * 4 + reg;
            int b = row & (BN - 1);
            int g = gid[b];
            float own = 0.f;
#pragma unroll
            for (int gt = 0; gt < 8; ++gt) {
                float v = acc[tile][gt][reg];
                Dotb[(size_t)row * KG + gt * 16 + m] = (unsigned short)f2bf(v);
                if ((g >> 4) == gt) own = v;
            }
            float rn = __shfl(tile ? s1 : s0, q * 4 + reg, 64);
            if ((g & 15) == m) {
                float d2 = fmaxf(rn - 2.f * own + cnormS[g], 0.f);
                atomicAdd(&h[g], sqrtf(sqrtf(d2)));   // sqrt(dist), dist = sqrt(d2)
            }
        }
    __syncthreads();
    if (t < KG) sqsPart[(size_t)blockIdx.x * KG + t] = h[t];
}

// K5b: density post-processing (per-block, from sqsPart partials) + loss, thread-per-row.
// Dot read as bf16: chunk c holds groups c*8..c*8+7; the positive in chunk c is index
// l (label), group = c*8+l, subject = c -> positive iff c != s.
__global__ __launch_bounds__(256) void k5b_loss(const unsigned short* __restrict__ Dotb,
                                                const int* __restrict__ gid,
                                                const float* __restrict__ sqsPart,
                                                const int* __restrict__ cnt,
                                                float* __restrict__ out) {
    __shared__ float tmp[KG], d1s[KG], qv[4];
    __shared__ float recipDen[KG];
    __shared__ float wsum[4];
    int t = threadIdx.x;
    // ---- density (threads 0..127; all threads hit barriers) ----
    float cntf = 0.f, d0 = 0.f, v = 0.f;
    if (t < KG) {
        float ss = 0.f;
        for (int j = 0; j < 256; j += 4)
            ss += sqsPart[(size_t)j * KG + t] + sqsPart[(size_t)(j + 1) * KG + t] +
                  sqsPart[(size_t)(j + 2) * KG + t] + sqsPart[(size_t)(j + 3) * KG + t];
        cntf = 2.f * (float)cnt[t];
        d0 = (ss / cntf) / logf(cntf + 10.f);
        tmp[t] = d0;
    }
    __syncthreads();
    if (t < KG) {
        float dmax = -INFINITY;
        for (int j = 0; j < KG; ++j) dmax = fmaxf(dmax, tmp[j]);
        v = (cntf <= 1.f) ? dmax : d0;
        d1s[t] = v;
    }
    __syncthreads();
    if (t < KG) {
        int less = 0, eq = 0;
        for (int j = 0; j < KG; ++j) {
            float u = d1s[j];
            less += (u < v) ? 1 : 0;
            eq += (u == v) ? 1 : 0;
        }
        // quantile(0.1): idx 12.7 -> 0.3*v[12]+0.7*v[13]; quantile(0.9): 0.7*v[114]+0.3*v[115]
        const int ppos[4] = {12, 13, 114, 115};
        for (int qq = 0; qq < 4; ++qq)
            if (less <= ppos[qq] && ppos[qq] < less + eq) qv[qq] = v;
    }
    __syncthreads();
    if (t < KG) {
        float q10 = 0.3f * qv[0] + 0.7f * qv[1];
        float q90 = 0.7f * qv[2] + 0.3f * qv[3];
        tmp[t] = fminf(fmaxf(v, q10), q90);
    }
    __syncthreads();
    if (t < KG) {
        float sum = 0.f;
        for (int j = 0; j < KG; ++j) sum += tmp[j];
        float mean = sum / (float)KG;
        recipDen[t] = mean / (0.1f * tmp[t]);   // 1/den
    }
    __syncthreads();
    // ---- loss: one thread per row ----
    int row = blockIdx.x * 256 + t;
    int b = row & (BN - 1);
    int g = gid[b];
    int s = g >> 3, l = g & 7;
    const short8v* dp = (const short8v*)(Dotb + (size_t)row * KG);
    float mx = -INFINITY;
    float psave[16];
#pragma unroll
    for (int c = 0; c < 16; ++c) {
        short8v dv = dp[c];
        const float* rv = &recipDen[c * 8];
        float x[8];
#pragma unroll
        for (int j = 0; j < 8; ++j) {
            x[j] = bf2f((unsigned short)dv[j]) * rv[j];
            mx = fmaxf(mx, x[j]);
        }
        float sel = x[0];
#pragma unroll
        for (int j = 1; j < 8; ++j) sel = (j == l) ? x[j] : sel;
        psave[c] = sel;
    }
    float S = 0.f, P = 0.f;
#pragma unroll
    for (int j = 0; j < 16; ++j) {
        float pv = psave[j] - mx;
        float e = expf(pv);
        bool use = (j != s);
        S += use ? e : 0.f;
        P += use ? pv : 0.f;
    }
    // 113 masked-out entries contribute exp(0)=1 each to the softmax denominator
    float ll = logf(113.f + S) - P * (1.f / 15.f);
#pragma unroll
    for (int x = 32; x; x >>= 1) ll += __shfl_xor(ll, x, 64);
    int lane = t & 63, w = t >> 6;
    if (lane == 0) wsum[w] = ll;
    __syncthreads();
    if (t == 0) atomicAdd(out, (wsum[0] + wsum[1] + wsum[2] + wsum[3]) * (1.f / 32768.f));
}

extern "C" void kernel_launch(void* const* d_in, const int* in_sizes, int n_in,
                              void* d_out, int out_size, void* d_ws, size_t ws_size,
                              hipStream_t stream) {
    const float* X = (const float*)d_in[0];
    const int* subject = (const int*)d_in[1];
    const int* labels = (const int*)d_in[2];
    float* out = (float*)d_out;
    char* w = (char*)d_ws;
    int* gid = (int*)(w + 0);                          // 64 KB
    int* hist = (int*)(w + 65536);                     // 8 KB  (16 x 128)
    int* cnt = (int*)(w + 73728);                      // 512 B
    float* cnormPart = (float*)(w + 74240);            // 1 KB  (2 x 128)
    int* rowlist = (int*)(w + 131072);                 // 64 KB
    unsigned short* Cbf = (unsigned short*)(w + 262144);   // 256 KB
    float* sqsPart = (float*)(w + 524288);             // 128 KB (256 x 128)
    unsigned short* Dotb = (unsigned short*)(w + 2097152); // 8 MB (bf16 32768 x 128)

    hipMemsetAsync(out, 0, sizeof(float), stream);

    k0_gid<<<16, 1024, 0, stream>>>(subject, labels, gid, hist);
    k0c_scatter<<<16, 1024, 0, stream>>>(gid, hist, cnt, rowlist);
    k1_centroid<<<KG * 2, 256, 0, stream>>>(X, rowlist, cnt, Cbf, cnormPart);
    k5a_dot<<<256, 256, 0, stream>>>(X, Cbf, gid, cnormPart, Dotb, sqsPart);
    k5b_loss<<<128, 256, 0, stream>>>(Dotb, gid, sqsPart, cnt, out);
}